// Round 5
// baseline (757.277 us; speedup 1.0000x reference)
//
#include <hip/hip_runtime.h>
#include <math.h>

// ---------------------------------------------------------------------------
// LinSinkhornPRModel: sigmoid(dist2 - dist1) of two Sinkhorn divergences.
//   - f_aa self-term cancels in dist2-dist1 -> C_xx never built.
//   - R3: dual-direction round pass (row-LSE + column partials in ONE read of
//     C; CT matrices & transpose kernel eliminated; 160->84 MB/round).
//     Cost GEMM: fused hi/lo passes (one load per kc, 48 MFMAs), swapped
//     mfma operands -> dwordx4 epilogue stores, all 4 matrices in 1 launch.
//   - R4: compile fix (vector-element refs -> scalar arrays/local temps).
// ---------------------------------------------------------------------------

typedef __attribute__((ext_vector_type(8))) short short8;
typedef __attribute__((ext_vector_type(4))) float f32x4;

#define LOG2E 1.4426950408889634
#define LN2   0.6931471805599453

__device__ __forceinline__ float exp2fast(float x){
#if __has_builtin(__builtin_amdgcn_exp2f)
    return __builtin_amdgcn_exp2f(x);
#else
    return exp2f(x);
#endif
}
__device__ __forceinline__ void lse2_upd(float& m, float& s, float v){
    float M2 = fmaxf(m, v);
    s = s * exp2fast(m - M2) + exp2fast(v - M2);
    m = M2;
}
__device__ __forceinline__ void lse2_merge(float& m, float& s, float mo, float so){
    float M2 = fmaxf(m, mo);
    s = s * exp2fast(m - M2) + so * exp2fast(mo - M2);
    m = M2;
}
__device__ __forceinline__ unsigned short f2bf(float x){
    unsigned u = __float_as_uint(x);
    unsigned r = u + 0x7fffu + ((u >> 16) & 1u);
    return (unsigned short)(r >> 16);
}
__device__ __forceinline__ float bf2f(unsigned short h){
    return __uint_as_float(((unsigned)h) << 16);
}

// ----------------------------- setup kernels -------------------------------

__global__ void k_transposeW(const float* __restrict__ W, float* __restrict__ WT){
    int b = blockIdx.x, t = threadIdx.x;   // WT[k][o] = W[o][k]
    WT[b * 128 + t] = W[t * 128 + b];
}

// 8 rows per block: T = X@W^T; writes bf16 split (th, tl) and hn = 0.5*||T||^2
__global__ __launch_bounds__(128)
void k_transform_all(const float* __restrict__ d, const float* __restrict__ si,
                     const float* __restrict__ sj, const float* __restrict__ WT,
                     unsigned short* __restrict__ th, unsigned short* __restrict__ tl,
                     float* __restrict__ hn)
{
    __shared__ float xs[8][128];
    __shared__ float red[16];
    const int t = threadIdx.x;
    const int r0 = blockIdx.x * 8;
    const float* src; int sr;
    if (r0 < 4096)      { src = d;  sr = r0; }
    else if (r0 < 6144) { src = si; sr = r0 - 4096; }
    else                { src = sj; sr = r0 - 6144; }
    for (int rr = 0; rr < 8; ++rr)
        xs[rr][t] = src[(size_t)(sr + rr) * 128 + t];
    __syncthreads();
    float acc[8];
#pragma unroll
    for (int rr = 0; rr < 8; ++rr) acc[rr] = 0.f;
    for (int k = 0; k < 128; ++k) {
        float wv = WT[k * 128 + t];
#pragma unroll
        for (int rr = 0; rr < 8; ++rr) acc[rr] = fmaf(xs[rr][k], wv, acc[rr]);
    }
#pragma unroll
    for (int rr = 0; rr < 8; ++rr) {
        float a = acc[rr];
        unsigned short hb = f2bf(a);
        th[(size_t)(r0 + rr) * 128 + t] = hb;
        tl[(size_t)(r0 + rr) * 128 + t] = f2bf(a - bf2f(hb));
        float sq = a * a;
#pragma unroll
        for (int o = 1; o < 64; o <<= 1) sq += __shfl_xor(sq, o);
        if ((t & 63) == 0) red[(t >> 6) * 8 + rr] = sq;
    }
    __syncthreads();
    if (t < 8) hn[r0 + t] = 0.5f * (red[t] + red[8 + t]);
}

__global__ void k_log_all(const float* __restrict__ h, const float* __restrict__ hi,
                          const float* __restrict__ hj, float* __restrict__ lg)
{
    int i = blockIdx.x * 256 + threadIdx.x;   // 8192 total
    float x;
    if (i < 4096)      x = h[i];
    else if (i < 6144) x = hi[i - 4096];
    else               x = hj[i - 6144];
    lg[i] = __log2f(x);
}

// ------------------------------ cost GEMM (MFMA) ---------------------------
// C[i][j] = max(hna[i] + hnb[j] - dot(A_i, B_j), 0); dot = hh + hl + lh
// (lo*lo dropped). mfma(bfrag, afrag) -> C^T fragment: lane holds one C row,
// 4 consecutive C cols in regs -> dwordx4 stores.
struct CostPair {
    const unsigned short *Ah, *Al, *Bh, *Bl;
    const float *hna, *hnb;
    float* C; int ldc; int nty;     // nty = valid blockIdx.y count
};
struct CostQuad { CostPair p[4]; };

__global__ __launch_bounds__(256)
void k_cost_mfma(CostQuad Q)
{
    CostPair P = Q.p[blockIdx.z];
    if ((int)blockIdx.y >= P.nty) return;
    const int i0 = blockIdx.y * 128, j0 = blockIdx.x * 128;
    const int w = threadIdx.x >> 6, lane = threadIdx.x & 63;
    const int ar = i0 + (w >> 1) * 64;
    const int bc = j0 + (w & 1) * 64;
    const int lrow = lane & 15;
    const int kgrp = (lane >> 4) * 8;

    f32x4 acc[4][4];
#pragma unroll
    for (int a = 0; a < 4; ++a)
#pragma unroll
        for (int c = 0; c < 4; ++c) acc[a][c] = (f32x4){0.f, 0.f, 0.f, 0.f};

#pragma unroll
    for (int kc = 0; kc < 128; kc += 32) {
        short8 ah[4], al[4], bh[4], bl[4];
#pragma unroll
        for (int f = 0; f < 4; ++f) {
            size_t aoff = (size_t)(ar + f * 16 + lrow) * 128 + kc + kgrp;
            size_t boff = (size_t)(bc + f * 16 + lrow) * 128 + kc + kgrp;
            ah[f] = *reinterpret_cast<const short8*>(P.Ah + aoff);
            al[f] = *reinterpret_cast<const short8*>(P.Al + aoff);
            bh[f] = *reinterpret_cast<const short8*>(P.Bh + boff);
            bl[f] = *reinterpret_cast<const short8*>(P.Bl + boff);
        }
#pragma unroll
        for (int fi = 0; fi < 4; ++fi)
#pragma unroll
            for (int fj = 0; fj < 4; ++fj) {
                acc[fi][fj] = __builtin_amdgcn_mfma_f32_16x16x32_bf16(bh[fj], ah[fi], acc[fi][fj], 0, 0, 0);
                acc[fi][fj] = __builtin_amdgcn_mfma_f32_16x16x32_bf16(bl[fj], ah[fi], acc[fi][fj], 0, 0, 0);
                acc[fi][fj] = __builtin_amdgcn_mfma_f32_16x16x32_bf16(bh[fj], al[fi], acc[fi][fj], 0, 0, 0);
            }
    }
    // D' = C^T fragment: C-row = lane&15, C-col = (lane>>4)*4 + reg
    const int rloc = lane & 15, cloc = (lane >> 4) * 4;
#pragma unroll
    for (int fi = 0; fi < 4; ++fi) {
        int crow = ar + fi * 16 + rloc;
        float ha = P.hna[crow];
#pragma unroll
        for (int fj = 0; fj < 4; ++fj) {
            int ccol = bc + fj * 16 + cloc;
            f32x4 hb = *reinterpret_cast<const f32x4*>(P.hnb + ccol);
            f32x4 v;
#pragma unroll
            for (int e = 0; e < 4; ++e)
                v[e] = fmaxf(ha + hb[e] - acc[fi][fj][e], 0.f);
            *reinterpret_cast<f32x4*>(P.C + (size_t)crow * P.ldc + ccol) = v;
        }
    }
}

// ------------------------------ round kernels ------------------------------
// Dual pass over C (rows x 2048): row-LSE -> f update + next-round WA weight;
// column-LSE partials (merged across the block's 4 waves in LDS) -> combine.
// All in log2 domain: v = w - C*ie2.

#define RPW 8          // rows per wave
#define BROWS 32       // rows per block

struct DTask {
    const float* C; const float* WB; const float* WA;
    const float* fold; float* fout; float* fwout;
    float* pm; float* ps; const float* la;
    int blk0;
};
struct YTask {
    const float* C; const float* Wv; const float* fold;
    float* vout; float* wout; const float* logself;
    int blk0;
};
struct RArgs2 {
    DTask dt[2]; YTask yt[2];
    float ie2, epsln2, ie2n, alpha, beta;
};

__global__ __launch_bounds__(256)
void k_round_dual(RArgs2 A)
{
    __shared__ float lm[2048], ls[2048];
    const int b = blockIdx.x;
    const int w = threadIdx.x >> 6, lane = threadIdx.x & 63;
    const float ie2 = A.ie2;

    if (b >= A.yt[0].blk0) {
        // ---- symmetric row-only task (g_bb update) ----
        YTask T = (b >= A.yt[1].blk0) ? A.yt[1] : A.yt[0];
        const int row0 = (b - T.blk0) * BROWS + w * RPW;
        const f32x4* W4 = reinterpret_cast<const f32x4*>(T.Wv);
        f32x4 wv[8];
#pragma unroll
        for (int k = 0; k < 8; ++k) wv[k] = W4[lane + 64 * k];
        float rm[8], rs[8];
#pragma unroll
        for (int rr = 0; rr < 8; ++rr) {
            const int row = row0 + rr;
            const f32x4* C4 = reinterpret_cast<const f32x4*>(T.C) + (size_t)row * 512;
            float m = -INFINITY, s = 0.f;
#pragma unroll
            for (int k = 0; k < 8; ++k) {
                f32x4 c = C4[lane + 64 * k];
#pragma unroll
                for (int e = 0; e < 4; ++e)
                    lse2_upd(m, s, fmaf(c[e], -ie2, wv[k][e]));
            }
            rm[rr] = m; rs[rr] = s;
        }
#pragma unroll
        for (int rr = 0; rr < 8; ++rr)
#pragma unroll
            for (int o = 1; o < 64; o <<= 1) {
                float mo = __shfl_xor(rm[rr], o), so = __shfl_xor(rs[rr], o);
                lse2_merge(rm[rr], rs[rr], mo, so);
            }
        if (lane == 0) {
#pragma unroll
            for (int rr = 0; rr < 8; ++rr) {
                int row = row0 + rr;
                float val  = -A.epsln2 * (rm[rr] + __log2f(rs[rr]));
                float vnew = A.alpha * T.fold[row] + A.beta * val;
                T.vout[row] = vnew;
                T.wout[row] = fmaf(vnew, A.ie2n, T.logself[row]);
            }
        }
        return;
    }

    // ---- dual xy task ----
    DTask T = (b >= A.dt[1].blk0) ? A.dt[1] : A.dt[0];
    const int blkl = b - T.blk0;
    const int row0 = blkl * BROWS + w * RPW;
    const f32x4* WB4 = reinterpret_cast<const f32x4*>(T.WB);
    f32x4 wb[8];
#pragma unroll
    for (int k = 0; k < 8; ++k) wb[k] = WB4[lane + 64 * k];

    float mc[8][4], sc[8][4];
#pragma unroll
    for (int k = 0; k < 8; ++k)
#pragma unroll
        for (int e = 0; e < 4; ++e) { mc[k][e] = -INFINITY; sc[k][e] = 0.f; }

    float rm[8], rs[8];
#pragma unroll
    for (int rr = 0; rr < 8; ++rr) {
        const int row = row0 + rr;
        const float wa = T.WA[row];
        const f32x4* C4 = reinterpret_cast<const f32x4*>(T.C) + (size_t)row * 512;
        float m = -INFINITY, s = 0.f;
#pragma unroll
        for (int k = 0; k < 8; ++k) {
            f32x4 c = C4[lane + 64 * k];
            float u0 = c[0] * -ie2, u1 = c[1] * -ie2, u2 = c[2] * -ie2, u3 = c[3] * -ie2;
            lse2_upd(m, s, u0 + wb[k][0]);
            lse2_upd(m, s, u1 + wb[k][1]);
            lse2_upd(m, s, u2 + wb[k][2]);
            lse2_upd(m, s, u3 + wb[k][3]);
            lse2_upd(mc[k][0], sc[k][0], u0 + wa);
            lse2_upd(mc[k][1], sc[k][1], u1 + wa);
            lse2_upd(mc[k][2], sc[k][2], u2 + wa);
            lse2_upd(mc[k][3], sc[k][3], u3 + wa);
        }
        rm[rr] = m; rs[rr] = s;
    }
    // row outputs
#pragma unroll
    for (int rr = 0; rr < 8; ++rr)
#pragma unroll
        for (int o = 1; o < 64; o <<= 1) {
            float mo = __shfl_xor(rm[rr], o), so = __shfl_xor(rs[rr], o);
            lse2_merge(rm[rr], rs[rr], mo, so);
        }
    if (lane == 0) {
#pragma unroll
        for (int rr = 0; rr < 8; ++rr) {
            int row = row0 + rr;
            float val  = -A.epsln2 * (rm[rr] + __log2f(rs[rr]));
            float vnew = A.alpha * T.fold[row] + A.beta * val;
            T.fout[row] = vnew;
            T.fwout[row] = fmaf(vnew, A.ie2n, T.la[row]);
        }
    }
    // column partial merge across the 4 waves (4 LDS phases)
#pragma unroll
    for (int p = 0; p < 4; ++p) {
        if (w == p) {
#pragma unroll
            for (int k = 0; k < 8; ++k) {
                int c4 = 4 * (lane + 64 * k);
                if (p == 0) {
#pragma unroll
                    for (int e = 0; e < 4; ++e) { lm[c4 + e] = mc[k][e]; ls[c4 + e] = sc[k][e]; }
                } else {
#pragma unroll
                    for (int e = 0; e < 4; ++e) {
                        float om = lm[c4 + e], os = ls[c4 + e];
                        lse2_merge(om, os, mc[k][e], sc[k][e]);
                        lm[c4 + e] = om; ls[c4 + e] = os;
                    }
                }
            }
        }
        __syncthreads();
    }
    // write block partial (coalesced f32x4)
    {
        float* pm = T.pm + (size_t)blkl * 2048;
        float* ps = T.ps + (size_t)blkl * 2048;
#pragma unroll
        for (int q = 0; q < 2; ++q) {
            int t4 = threadIdx.x + q * 256;
            *reinterpret_cast<f32x4*>(pm + 4 * t4) = *reinterpret_cast<const f32x4*>(&lm[4 * t4]);
            *reinterpret_cast<f32x4*>(ps + 4 * t4) = *reinterpret_cast<const f32x4*>(&ls[4 * t4]);
        }
    }
}

// combine: 16 threads per column over nchunk block-partials -> g update
struct CTask {
    const float* pm; const float* ps; const float* gold; const float* lb;
    float* gout; float* gwout;
};

__global__ __launch_bounds__(256)
void k_comb(CTask T0, CTask T1, int nchunk, float epsln2, float ie2n,
            float alpha, float beta)
{
    CTask T = blockIdx.z ? T1 : T0;
    const int jl = threadIdx.x & 15;
    const int j  = blockIdx.x * 16 + jl;
    const int cg = threadIdx.x >> 4;
    float m = -INFINITY, s = 0.f;
    for (int c = cg; c < nchunk; c += 16)
        lse2_merge(m, s, T.pm[(size_t)c * 2048 + j], T.ps[(size_t)c * 2048 + j]);
#pragma unroll
    for (int o = 16; o <= 32; o <<= 1) {
        float mo = __shfl_xor(m, o), so = __shfl_xor(s, o);
        lse2_merge(m, s, mo, so);
    }
    __shared__ float smm[4][16], sss[4][16];
    const int lane = threadIdx.x & 63, w = threadIdx.x >> 6;
    if (lane < 16) { smm[w][lane] = m; sss[w][lane] = s; }
    __syncthreads();
    if (threadIdx.x < 16) {
        m = smm[0][jl]; s = sss[0][jl];
        for (int q = 1; q < 4; ++q) lse2_merge(m, s, smm[q][jl], sss[q][jl]);
        float val  = -epsln2 * (m + __log2f(s));
        float gnew = alpha * T.gold[j] + beta * val;
        T.gout[j] = gnew;
        T.gwout[j] = fmaf(gnew, ie2n, T.lb[j]);
    }
}

// ------------------------------ final reduce -------------------------------
__global__ __launch_bounds__(1024)
void k_final(const float* __restrict__ h, const float* __restrict__ hi,
             const float* __restrict__ hj,
             const float* __restrict__ f1f, const float* __restrict__ f2f,
             const float* __restrict__ g1f, const float* __restrict__ gb1f,
             const float* __restrict__ g2f, const float* __restrict__ gb2f,
             int N, int M, float* __restrict__ out)
{
    float acc = 0.f;
    for (int i = threadIdx.x; i < N; i += 1024)
        acc += h[i] * (f2f[i] - f1f[i]);
    for (int j = threadIdx.x; j < M; j += 1024)
        acc += hj[j] * (g2f[j] - gb2f[j]) - hi[j] * (g1f[j] - gb1f[j]);
#pragma unroll
    for (int o = 32; o; o >>= 1) acc += __shfl_xor(acc, o);
    __shared__ float red[16];
    const int lane = threadIdx.x & 63, w = threadIdx.x >> 6;
    if (lane == 0) red[w] = acc;
    __syncthreads();
    if (threadIdx.x == 0) {
        float t = 0.f;
        for (int q = 0; q < 16; ++q) t += red[q];
        out[0] = 1.f / (1.f + expf(-t));   // SCALING_FACTOR = 1
    }
}

// ------------------------------ orchestration ------------------------------

extern "C" void kernel_launch(void* const* d_in, const int* in_sizes, int n_in,
                              void* d_out, int out_size, void* d_ws, size_t ws_size,
                              hipStream_t stream)
{
    const float* d  = (const float*)d_in[0];
    const float* si = (const float*)d_in[1];
    const float* sj = (const float*)d_in[2];
    const float* h  = (const float*)d_in[3];
    const float* hi = (const float*)d_in[4];
    const float* hj = (const float*)d_in[5];
    const float* W  = (const float*)d_in[6];
    float* out = (float*)d_out;

    const int N = 4096, M = 2048;
    const int NBD = N / BROWS;   // 128 blocks per dual task
    const int NBY = M / BROWS;   // 64 blocks per yy task
    (void)in_sizes; (void)n_in; (void)out_size; (void)ws_size;

    float* ws = (float*)d_ws;
    size_t off = 0;
    auto alloc = [&](size_t n) { float* p = ws + off; off += (n + 63) & ~(size_t)63; return p; };

    float* WT    = alloc(128 * 128);
    float* lg2   = alloc(8192);
    float* hnAll = alloc(8192);
    unsigned short* thAll = (unsigned short*)alloc(8192 * 128 / 2);
    unsigned short* tlAll = (unsigned short*)alloc(8192 * 128 / 2);
    float* f1[2]  = { alloc(N), alloc(N) };
    float* f2[2]  = { alloc(N), alloc(N) };
    float* g1[2]  = { alloc(M), alloc(M) };
    float* g2[2]  = { alloc(M), alloc(M) };
    float* gb1[2] = { alloc(M), alloc(M) };
    float* gb2[2] = { alloc(M), alloc(M) };
    float* WA1[2] = { alloc(N), alloc(N) };
    float* WA2[2] = { alloc(N), alloc(N) };
    float* WB1[2] = { alloc(M), alloc(M) };
    float* WB2[2] = { alloc(M), alloc(M) };
    float* WY1[2] = { alloc(M), alloc(M) };
    float* WY2[2] = { alloc(M), alloc(M) };
    float* f1f = alloc(N); float* f2f = alloc(N);
    float* g1f = alloc(M); float* g2f = alloc(M);
    float* gb1f = alloc(M); float* gb2f = alloc(M);
    float* C1  = alloc((size_t)N * M);
    float* C2  = alloc((size_t)N * M);
    float* Cy1 = alloc((size_t)M * M);
    float* Cy2 = alloc((size_t)M * M);
    float* pm1 = alloc((size_t)NBD * 2048);
    float* ps1 = alloc((size_t)NBD * 2048);
    float* pm2 = alloc((size_t)NBD * 2048);
    float* ps2 = alloc((size_t)NBD * 2048);

    float* la2  = lg2;
    float* lbi2 = lg2 + 4096;
    float* lbj2 = lg2 + 6144;
    const float* hnx = hnAll;
    const float* hni = hnAll + 4096;
    const float* hnj = hnAll + 6144;
    const unsigned short* tdh  = thAll;
    const unsigned short* tdl  = tlAll;
    const unsigned short* tsih = thAll + (size_t)4096 * 128;
    const unsigned short* tsil = tlAll + (size_t)4096 * 128;
    const unsigned short* tsjh = thAll + (size_t)6144 * 128;
    const unsigned short* tsjl = tlAll + (size_t)6144 * 128;

    // ---- setup ----
    k_transposeW<<<128, 128, 0, stream>>>(W, WT);
    k_transform_all<<<1024, 128, 0, stream>>>(d, si, sj, WT, thAll, tlAll, hnAll);
    k_log_all<<<32, 256, 0, stream>>>(h, hi, hj, lg2);

    // ---- cost matrices: 4 GEMMs in one launch ----
    CostQuad Q;
    Q.p[0] = { tdh,  tdl,  tsih, tsil, hnx, hni, C1,  M, 32 };
    Q.p[1] = { tdh,  tdl,  tsjh, tsjl, hnx, hnj, C2,  M, 32 };
    Q.p[2] = { tsih, tsil, tsih, tsil, hni, hni, Cy1, M, 16 };
    Q.p[3] = { tsjh, tsjl, tsjh, tsjl, hnj, hnj, Cy2, M, 16 };
    k_cost_mfma<<<dim3(M / 128, N / 128, 4), 256, 0, stream>>>(Q);

    // ---- eps schedule ----
    double epsl[16]; int ne = 0;
    for (double sg = 32.0; sg > 0.05; sg *= 0.5) epsl[ne++] = sg * sg;
    epsl[ne++] = 0.05 * 0.05;   // ne == 11

    for (int r = 0; r <= ne + 1; ++r) {
        const bool init = (r == 0), fin = (r == ne + 1);
        const double eps  = init ? epsl[0] : (fin ? epsl[ne - 1] : epsl[r - 1]);
        const double epsn = (r + 1 <= ne) ? epsl[r] : epsl[ne - 1];
        const int in = init ? 0 : (r - 1) & 1;
        const int o  = r & 1;

        RArgs2 A;
        A.ie2    = (float)(LOG2E / eps);
        A.epsln2 = (float)(eps * LN2);
        A.ie2n   = (float)(LOG2E / epsn);
        A.alpha  = (init || fin) ? 0.0f : 0.5f;
        A.beta   = (init || fin) ? 1.0f : 0.5f;
        A.dt[0] = { C1, init ? lbi2 : WB1[in], init ? la2 : WA1[in], f1[in],
                    fin ? f1f : f1[o], WA1[o], pm1, ps1, la2, 0 };
        A.dt[1] = { C2, init ? lbj2 : WB2[in], init ? la2 : WA2[in], f2[in],
                    fin ? f2f : f2[o], WA2[o], pm2, ps2, la2, NBD };
        A.yt[0] = { Cy1, init ? lbi2 : WY1[in], gb1[in],
                    fin ? gb1f : gb1[o], WY1[o], lbi2, 2 * NBD };
        A.yt[1] = { Cy2, init ? lbj2 : WY2[in], gb2[in],
                    fin ? gb2f : gb2[o], WY2[o], lbj2, 2 * NBD + NBY };
        k_round_dual<<<2 * NBD + 2 * NBY, 256, 0, stream>>>(A);

        CTask c0 = { pm1, ps1, g1[in], lbi2, fin ? g1f : g1[o], WB1[o] };
        CTask c1 = { pm2, ps2, g2[in], lbj2, fin ? g2f : g2[o], WB2[o] };
        k_comb<<<dim3(M / 16, 1, 2), 256, 0, stream>>>(c0, c1, NBD,
            (float)(eps * LN2), (float)(LOG2E / epsn), A.alpha, A.beta);
    }

    k_final<<<1, 1024, 0, stream>>>(h, hi, hj, f1f, f2f, g1f, gb1f, g2f, gb2f, N, M, out);
}

// Round 6
// 509.163 us; speedup vs baseline: 1.4873x; 1.4873x over previous
//
#include <hip/hip_runtime.h>
#include <math.h>

// ---------------------------------------------------------------------------
// LinSinkhornPRModel: sigmoid(dist2 - dist1) of two Sinkhorn divergences.
//   - f_aa self-term cancels in dist2-dist1 -> C_xx never built.
//   - R3: dual-direction pass (row-LSE + col partials in ONE read of C).
//   - R5 regression post-mortem: 384-block grid = 1.5 blocks/CU -> latency
//     starvation (50us/round). R6: 16x1024 tiles -> 1536 blocks; BOTH
//     directions go through partials; all updates moved to k_comb2.
// ---------------------------------------------------------------------------

typedef __attribute__((ext_vector_type(8))) short short8;
typedef __attribute__((ext_vector_type(4))) float f32x4;

#define LOG2E 1.4426950408889634
#define LN2   0.6931471805599453

__device__ __forceinline__ float exp2fast(float x){
#if __has_builtin(__builtin_amdgcn_exp2f)
    return __builtin_amdgcn_exp2f(x);
#else
    return exp2f(x);
#endif
}
__device__ __forceinline__ void lse2_upd(float& m, float& s, float v){
    float M2 = fmaxf(m, v);
    s = s * exp2fast(m - M2) + exp2fast(v - M2);
    m = M2;
}
__device__ __forceinline__ void lse2_merge(float& m, float& s, float mo, float so){
    float M2 = fmaxf(m, mo);
    s = s * exp2fast(m - M2) + so * exp2fast(mo - M2);
    m = M2;
}
__device__ __forceinline__ unsigned short f2bf(float x){
    unsigned u = __float_as_uint(x);
    unsigned r = u + 0x7fffu + ((u >> 16) & 1u);
    return (unsigned short)(r >> 16);
}
__device__ __forceinline__ float bf2f(unsigned short h){
    return __uint_as_float(((unsigned)h) << 16);
}

// ----------------------------- setup kernels -------------------------------

__global__ void k_transposeW(const float* __restrict__ W, float* __restrict__ WT){
    int b = blockIdx.x, t = threadIdx.x;   // WT[k][o] = W[o][k]
    WT[b * 128 + t] = W[t * 128 + b];
}

__global__ __launch_bounds__(128)
void k_transform_all(const float* __restrict__ d, const float* __restrict__ si,
                     const float* __restrict__ sj, const float* __restrict__ WT,
                     unsigned short* __restrict__ th, unsigned short* __restrict__ tl,
                     float* __restrict__ hn)
{
    __shared__ float xs[8][128];
    __shared__ float red[16];
    const int t = threadIdx.x;
    const int r0 = blockIdx.x * 8;
    const float* src; int sr;
    if (r0 < 4096)      { src = d;  sr = r0; }
    else if (r0 < 6144) { src = si; sr = r0 - 4096; }
    else                { src = sj; sr = r0 - 6144; }
    for (int rr = 0; rr < 8; ++rr)
        xs[rr][t] = src[(size_t)(sr + rr) * 128 + t];
    __syncthreads();
    float acc[8];
#pragma unroll
    for (int rr = 0; rr < 8; ++rr) acc[rr] = 0.f;
    for (int k = 0; k < 128; ++k) {
        float wv = WT[k * 128 + t];
#pragma unroll
        for (int rr = 0; rr < 8; ++rr) acc[rr] = fmaf(xs[rr][k], wv, acc[rr]);
    }
#pragma unroll
    for (int rr = 0; rr < 8; ++rr) {
        float a = acc[rr];
        unsigned short hb = f2bf(a);
        th[(size_t)(r0 + rr) * 128 + t] = hb;
        tl[(size_t)(r0 + rr) * 128 + t] = f2bf(a - bf2f(hb));
        float sq = a * a;
#pragma unroll
        for (int o = 1; o < 64; o <<= 1) sq += __shfl_xor(sq, o);
        if ((t & 63) == 0) red[(t >> 6) * 8 + rr] = sq;
    }
    __syncthreads();
    if (t < 8) hn[r0 + t] = 0.5f * (red[t] + red[8 + t]);
}

__global__ void k_log_all(const float* __restrict__ h, const float* __restrict__ hi,
                          const float* __restrict__ hj, float* __restrict__ lg)
{
    int i = blockIdx.x * 256 + threadIdx.x;   // 8192 total
    float x;
    if (i < 4096)      x = h[i];
    else if (i < 6144) x = hi[i - 4096];
    else               x = hj[i - 6144];
    lg[i] = __log2f(x);
}

// ------------------------------ cost GEMM (MFMA) ---------------------------
struct CostPair {
    const unsigned short *Ah, *Al, *Bh, *Bl;
    const float *hna, *hnb;
    float* C; int ldc; int nty;
};
struct CostQuad { CostPair p[4]; };

__global__ __launch_bounds__(256)
void k_cost_mfma(CostQuad Q)
{
    CostPair P = Q.p[blockIdx.z];
    if ((int)blockIdx.y >= P.nty) return;
    const int i0 = blockIdx.y * 128, j0 = blockIdx.x * 128;
    const int w = threadIdx.x >> 6, lane = threadIdx.x & 63;
    const int ar = i0 + (w >> 1) * 64;
    const int bc = j0 + (w & 1) * 64;
    const int lrow = lane & 15;
    const int kgrp = (lane >> 4) * 8;

    f32x4 acc[4][4];
#pragma unroll
    for (int a = 0; a < 4; ++a)
#pragma unroll
        for (int c = 0; c < 4; ++c) acc[a][c] = (f32x4){0.f, 0.f, 0.f, 0.f};

#pragma unroll
    for (int kc = 0; kc < 128; kc += 32) {
        short8 ah[4], al[4], bh[4], bl[4];
#pragma unroll
        for (int f = 0; f < 4; ++f) {
            size_t aoff = (size_t)(ar + f * 16 + lrow) * 128 + kc + kgrp;
            size_t boff = (size_t)(bc + f * 16 + lrow) * 128 + kc + kgrp;
            ah[f] = *reinterpret_cast<const short8*>(P.Ah + aoff);
            al[f] = *reinterpret_cast<const short8*>(P.Al + aoff);
            bh[f] = *reinterpret_cast<const short8*>(P.Bh + boff);
            bl[f] = *reinterpret_cast<const short8*>(P.Bl + boff);
        }
#pragma unroll
        for (int fi = 0; fi < 4; ++fi)
#pragma unroll
            for (int fj = 0; fj < 4; ++fj) {
                acc[fi][fj] = __builtin_amdgcn_mfma_f32_16x16x32_bf16(bh[fj], ah[fi], acc[fi][fj], 0, 0, 0);
                acc[fi][fj] = __builtin_amdgcn_mfma_f32_16x16x32_bf16(bl[fj], ah[fi], acc[fi][fj], 0, 0, 0);
                acc[fi][fj] = __builtin_amdgcn_mfma_f32_16x16x32_bf16(bh[fj], al[fi], acc[fi][fj], 0, 0, 0);
            }
    }
    const int rloc = lane & 15, cloc = (lane >> 4) * 4;
#pragma unroll
    for (int fi = 0; fi < 4; ++fi) {
        int crow = ar + fi * 16 + rloc;
        float ha = P.hna[crow];
#pragma unroll
        for (int fj = 0; fj < 4; ++fj) {
            int ccol = bc + fj * 16 + cloc;
            f32x4 hb = *reinterpret_cast<const f32x4*>(P.hnb + ccol);
            f32x4 v;
#pragma unroll
            for (int e = 0; e < 4; ++e)
                v[e] = fmaxf(ha + hb[e] - acc[fi][fj][e], 0.f);
            *reinterpret_cast<f32x4*>(P.C + (size_t)crow * P.ldc + ccol) = v;
        }
    }
}

// ------------------------------ round kernel -------------------------------
// Tile 16 rows x 1024 cols. Dual tasks: row-LSE partials (per col-half) AND
// column-LSE partials (per 16-row chunk, merged across 4 waves in LDS).
// YY tasks: row-LSE partials only. All updates happen in k_comb2.

struct R2Task {          // C is rows x 2048
    const float* C; const float* WB; const float* WA;
    float* pm; float* ps;        // [nchunk=rows/16][2048]
    float* frm; float* frs;      // [2][rows]
    int blk0;
};
struct R2YTask {
    const float* C; const float* Wv;
    float* yrm; float* yrs;      // [2][2048]
    int blk0;
};
struct R2Args {
    R2Task d[2]; R2YTask y[2];
    float ie2; int yblk0;
};

__global__ __launch_bounds__(256)
void k_round2(R2Args A)
{
    const int b = blockIdx.x;
    const int w = threadIdx.x >> 6, lane = threadIdx.x & 63;
    const float ie2 = A.ie2;

    if (b >= A.yblk0) {
        // ---- yy row-only tile ----
        R2YTask T = (b >= A.y[1].blk0) ? A.y[1] : A.y[0];
        const int blk = b - T.blk0;
        const int rowchunk = blk >> 1, h = blk & 1;
        const int row0 = rowchunk * 16 + w * 4;
        const int cb4 = h * 256;
        const f32x4* W4 = reinterpret_cast<const f32x4*>(T.Wv) + cb4;
        f32x4 wv[4];
#pragma unroll
        for (int k = 0; k < 4; ++k) wv[k] = W4[lane + 64 * k];
#pragma unroll
        for (int rr = 0; rr < 4; ++rr) {
            const int row = row0 + rr;
            const f32x4* C4 = reinterpret_cast<const f32x4*>(T.C) + (size_t)row * 512 + cb4;
            float m = -INFINITY, s = 0.f;
#pragma unroll
            for (int k = 0; k < 4; ++k) {
                f32x4 c = C4[lane + 64 * k];
#pragma unroll
                for (int e = 0; e < 4; ++e)
                    lse2_upd(m, s, fmaf(c[e], -ie2, wv[k][e]));
            }
#pragma unroll
            for (int o = 1; o < 64; o <<= 1) {
                float mo = __shfl_xor(m, o), so = __shfl_xor(s, o);
                lse2_merge(m, s, mo, so);
            }
            if (lane == 0) { T.yrm[h * 2048 + row] = m; T.yrs[h * 2048 + row] = s; }
        }
        return;
    }

    // ---- dual xy tile ----
    __shared__ float lm[1024], ls[1024];
    R2Task T = (b >= A.d[1].blk0) ? A.d[1] : A.d[0];
    const int blk = b - T.blk0;
    const int rowchunk = blk >> 1, h = blk & 1;
    const int row0 = rowchunk * 16 + w * 4;
    const int cb4 = h * 256;
    const f32x4* WB4 = reinterpret_cast<const f32x4*>(T.WB) + cb4;
    f32x4 wb[4];
#pragma unroll
    for (int k = 0; k < 4; ++k) wb[k] = WB4[lane + 64 * k];

    float mc[4][4], sc[4][4];
#pragma unroll
    for (int k = 0; k < 4; ++k)
#pragma unroll
        for (int e = 0; e < 4; ++e) { mc[k][e] = -INFINITY; sc[k][e] = 0.f; }

#pragma unroll
    for (int rr = 0; rr < 4; ++rr) {
        const int row = row0 + rr;
        const float wa = T.WA[row];
        const f32x4* C4 = reinterpret_cast<const f32x4*>(T.C) + (size_t)row * 512 + cb4;
        float m = -INFINITY, s = 0.f;
#pragma unroll
        for (int k = 0; k < 4; ++k) {
            f32x4 c = C4[lane + 64 * k];
            float u0 = c[0] * -ie2, u1 = c[1] * -ie2;
            float u2 = c[2] * -ie2, u3 = c[3] * -ie2;
            lse2_upd(m, s, u0 + wb[k][0]);
            lse2_upd(m, s, u1 + wb[k][1]);
            lse2_upd(m, s, u2 + wb[k][2]);
            lse2_upd(m, s, u3 + wb[k][3]);
            lse2_upd(mc[k][0], sc[k][0], u0 + wa);
            lse2_upd(mc[k][1], sc[k][1], u1 + wa);
            lse2_upd(mc[k][2], sc[k][2], u2 + wa);
            lse2_upd(mc[k][3], sc[k][3], u3 + wa);
        }
#pragma unroll
        for (int o = 1; o < 64; o <<= 1) {
            float mo = __shfl_xor(m, o), so = __shfl_xor(s, o);
            lse2_merge(m, s, mo, so);
        }
        if (lane == 0) { T.frm[h * 4096 + row] = m; T.frs[h * 4096 + row] = s; }
    }

    // merge col accums across the 4 waves
#pragma unroll
    for (int p = 0; p < 4; ++p) {
        if (w == p) {
#pragma unroll
            for (int k = 0; k < 4; ++k) {
                int c4 = 4 * (lane + 64 * k);
                if (p == 0) {
#pragma unroll
                    for (int e = 0; e < 4; ++e) { lm[c4 + e] = mc[k][e]; ls[c4 + e] = sc[k][e]; }
                } else {
#pragma unroll
                    for (int e = 0; e < 4; ++e) {
                        float om = lm[c4 + e], os = ls[c4 + e];
                        lse2_merge(om, os, mc[k][e], sc[k][e]);
                        lm[c4 + e] = om; ls[c4 + e] = os;
                    }
                }
            }
        }
        __syncthreads();
    }
    {
        size_t o = (size_t)rowchunk * 2048 + h * 1024 + 4 * threadIdx.x;
        *reinterpret_cast<f32x4*>(T.pm + o) = *reinterpret_cast<const f32x4*>(&lm[4 * threadIdx.x]);
        *reinterpret_cast<f32x4*>(T.ps + o) = *reinterpret_cast<const f32x4*>(&ls[4 * threadIdx.x]);
    }
}

// ------------------------------ combine kernel -----------------------------
// Range A [0,128): column combines (g1,g2), 32 cols x 8 chunk-groups/block.
// Range B [128,160): f-row combines (2 col-half partials per row).
// Range C [160,176): yy-row combines.

struct CombA { const float* pm; const float* ps; const float* gold;
               const float* lb; float* gout; float* gwout; };
struct CombR { const float* rm; const float* rs; const float* fold;
               const float* lsf; float* vout; float* wout; int nrows; };
struct C2Args {
    CombA a[2]; CombR rB[2]; CombR rC[2];
    float epsln2, ie2n, alpha, beta;
};

__global__ __launch_bounds__(256)
void k_comb2(C2Args A)
{
    const int b = blockIdx.x;
    const int tid = threadIdx.x;
    const int lane = tid & 63, w = tid >> 6;
    if (b < 128) {
        CombA T = A.a[b >> 6];
        const int bb = b & 63;
        const int jl = tid & 31, cg = tid >> 5;      // 8 chunk groups
        const int j = bb * 32 + jl;
        float m = -INFINITY, s = 0.f;
        for (int c = cg; c < 256; c += 8)
            lse2_merge(m, s, T.pm[(size_t)c * 2048 + j], T.ps[(size_t)c * 2048 + j]);
        {
            float mo = __shfl_xor(m, 32), so = __shfl_xor(s, 32);
            lse2_merge(m, s, mo, so);
        }
        __shared__ float smm[4][32], sss[4][32];
        if (lane < 32) { smm[w][lane] = m; sss[w][lane] = s; }
        __syncthreads();
        if (tid < 32) {
            m = smm[0][tid]; s = sss[0][tid];
            for (int q = 1; q < 4; ++q) lse2_merge(m, s, smm[q][tid], sss[q][tid]);
            float val = -A.epsln2 * (m + __log2f(s));
            float gnew = A.alpha * T.gold[j] + A.beta * val;
            T.gout[j] = gnew;
            T.gwout[j] = fmaf(gnew, A.ie2n, T.lb[j]);
        }
        return;
    }
    CombR T = (b < 160) ? A.rB[(b - 128) >> 4] : A.rC[(b - 160) >> 3];
    const int row = ((b < 160) ? ((b - 128) & 15) : ((b - 160) & 7)) * 256 + tid;
    float m = T.rm[row], s = T.rs[row];
    lse2_merge(m, s, T.rm[T.nrows + row], T.rs[T.nrows + row]);
    float val = -A.epsln2 * (m + __log2f(s));
    float vnew = A.alpha * T.fold[row] + A.beta * val;
    T.vout[row] = vnew;
    T.wout[row] = fmaf(vnew, A.ie2n, T.lsf[row]);
}

// ------------------------------ final reduce -------------------------------
__global__ __launch_bounds__(1024)
void k_final(const float* __restrict__ h, const float* __restrict__ hi,
             const float* __restrict__ hj,
             const float* __restrict__ f1f, const float* __restrict__ f2f,
             const float* __restrict__ g1f, const float* __restrict__ gb1f,
             const float* __restrict__ g2f, const float* __restrict__ gb2f,
             int N, int M, float* __restrict__ out)
{
    float acc = 0.f;
    for (int i = threadIdx.x; i < N; i += 1024)
        acc += h[i] * (f2f[i] - f1f[i]);
    for (int j = threadIdx.x; j < M; j += 1024)
        acc += hj[j] * (g2f[j] - gb2f[j]) - hi[j] * (g1f[j] - gb1f[j]);
#pragma unroll
    for (int o = 32; o; o >>= 1) acc += __shfl_xor(acc, o);
    __shared__ float red[16];
    const int lane = threadIdx.x & 63, w = threadIdx.x >> 6;
    if (lane == 0) red[w] = acc;
    __syncthreads();
    if (threadIdx.x == 0) {
        float t = 0.f;
        for (int q = 0; q < 16; ++q) t += red[q];
        out[0] = 1.f / (1.f + expf(-t));   // SCALING_FACTOR = 1
    }
}

// ------------------------------ orchestration ------------------------------

extern "C" void kernel_launch(void* const* d_in, const int* in_sizes, int n_in,
                              void* d_out, int out_size, void* d_ws, size_t ws_size,
                              hipStream_t stream)
{
    const float* d  = (const float*)d_in[0];
    const float* si = (const float*)d_in[1];
    const float* sj = (const float*)d_in[2];
    const float* h  = (const float*)d_in[3];
    const float* hi = (const float*)d_in[4];
    const float* hj = (const float*)d_in[5];
    const float* W  = (const float*)d_in[6];
    float* out = (float*)d_out;

    const int N = 4096, M = 2048;
    (void)in_sizes; (void)n_in; (void)out_size; (void)ws_size;

    float* ws = (float*)d_ws;
    size_t off = 0;
    auto alloc = [&](size_t n) { float* p = ws + off; off += (n + 63) & ~(size_t)63; return p; };

    float* WT    = alloc(128 * 128);
    float* lg2   = alloc(8192);
    float* hnAll = alloc(8192);
    unsigned short* thAll = (unsigned short*)alloc(8192 * 128 / 2);
    unsigned short* tlAll = (unsigned short*)alloc(8192 * 128 / 2);
    float* f1[2]  = { alloc(N), alloc(N) };
    float* f2[2]  = { alloc(N), alloc(N) };
    float* g1[2]  = { alloc(M), alloc(M) };
    float* g2[2]  = { alloc(M), alloc(M) };
    float* gb1[2] = { alloc(M), alloc(M) };
    float* gb2[2] = { alloc(M), alloc(M) };
    float* WA1[2] = { alloc(N), alloc(N) };
    float* WA2[2] = { alloc(N), alloc(N) };
    float* WB1[2] = { alloc(M), alloc(M) };
    float* WB2[2] = { alloc(M), alloc(M) };
    float* WY1[2] = { alloc(M), alloc(M) };
    float* WY2[2] = { alloc(M), alloc(M) };
    float* f1f = alloc(N); float* f2f = alloc(N);
    float* g1f = alloc(M); float* g2f = alloc(M);
    float* gb1f = alloc(M); float* gb2f = alloc(M);
    float* C1  = alloc((size_t)N * M);
    float* C2  = alloc((size_t)N * M);
    float* Cy1 = alloc((size_t)M * M);
    float* Cy2 = alloc((size_t)M * M);
    float* pm1 = alloc((size_t)256 * 2048);
    float* ps1 = alloc((size_t)256 * 2048);
    float* pm2 = alloc((size_t)256 * 2048);
    float* ps2 = alloc((size_t)256 * 2048);
    float* frm1 = alloc(2 * 4096); float* frs1 = alloc(2 * 4096);
    float* frm2 = alloc(2 * 4096); float* frs2 = alloc(2 * 4096);
    float* yrm1 = alloc(2 * 2048); float* yrs1 = alloc(2 * 2048);
    float* yrm2 = alloc(2 * 2048); float* yrs2 = alloc(2 * 2048);

    float* la2  = lg2;
    float* lbi2 = lg2 + 4096;
    float* lbj2 = lg2 + 6144;
    const float* hnx = hnAll;
    const float* hni = hnAll + 4096;
    const float* hnj = hnAll + 6144;
    const unsigned short* tdh  = thAll;
    const unsigned short* tdl  = tlAll;
    const unsigned short* tsih = thAll + (size_t)4096 * 128;
    const unsigned short* tsil = tlAll + (size_t)4096 * 128;
    const unsigned short* tsjh = thAll + (size_t)6144 * 128;
    const unsigned short* tsjl = tlAll + (size_t)6144 * 128;

    // ---- setup ----
    k_transposeW<<<128, 128, 0, stream>>>(W, WT);
    k_transform_all<<<1024, 128, 0, stream>>>(d, si, sj, WT, thAll, tlAll, hnAll);
    k_log_all<<<32, 256, 0, stream>>>(h, hi, hj, lg2);

    // ---- cost matrices: 4 GEMMs in one launch ----
    CostQuad Q;
    Q.p[0] = { tdh,  tdl,  tsih, tsil, hnx, hni, C1,  M, 32 };
    Q.p[1] = { tdh,  tdl,  tsjh, tsjl, hnx, hnj, C2,  M, 32 };
    Q.p[2] = { tsih, tsil, tsih, tsil, hni, hni, Cy1, M, 16 };
    Q.p[3] = { tsjh, tsjl, tsjh, tsjl, hnj, hnj, Cy2, M, 16 };
    k_cost_mfma<<<dim3(M / 128, N / 128, 4), 256, 0, stream>>>(Q);

    // ---- eps schedule ----
    double epsl[16]; int ne = 0;
    for (double sg = 32.0; sg > 0.05; sg *= 0.5) epsl[ne++] = sg * sg;
    epsl[ne++] = 0.05 * 0.05;   // ne == 11

    for (int r = 0; r <= ne + 1; ++r) {
        const bool init = (r == 0), fin = (r == ne + 1);
        const double eps  = init ? epsl[0] : (fin ? epsl[ne - 1] : epsl[r - 1]);
        const double epsn = (r + 1 <= ne) ? epsl[r] : epsl[ne - 1];
        const int in = init ? 0 : (r - 1) & 1;
        const int o  = r & 1;

        R2Args RA;
        RA.ie2 = (float)(LOG2E / eps);
        RA.yblk0 = 1024;
        RA.d[0] = { C1, init ? lbi2 : WB1[in], init ? la2 : WA1[in], pm1, ps1, frm1, frs1, 0 };
        RA.d[1] = { C2, init ? lbj2 : WB2[in], init ? la2 : WA2[in], pm2, ps2, frm2, frs2, 512 };
        RA.y[0] = { Cy1, init ? lbi2 : WY1[in], yrm1, yrs1, 1024 };
        RA.y[1] = { Cy2, init ? lbj2 : WY2[in], yrm2, yrs2, 1280 };
        k_round2<<<1536, 256, 0, stream>>>(RA);

        C2Args CA;
        CA.epsln2 = (float)(eps * LN2);
        CA.ie2n   = (float)(LOG2E / epsn);
        CA.alpha  = (init || fin) ? 0.0f : 0.5f;
        CA.beta   = (init || fin) ? 1.0f : 0.5f;
        CA.a[0]  = { pm1, ps1, g1[in], lbi2, fin ? g1f : g1[o], WB1[o] };
        CA.a[1]  = { pm2, ps2, g2[in], lbj2, fin ? g2f : g2[o], WB2[o] };
        CA.rB[0] = { frm1, frs1, f1[in], la2, fin ? f1f : f1[o], WA1[o], 4096 };
        CA.rB[1] = { frm2, frs2, f2[in], la2, fin ? f2f : f2[o], WA2[o], 4096 };
        CA.rC[0] = { yrm1, yrs1, gb1[in], lbi2, fin ? gb1f : gb1[o], WY1[o], 2048 };
        CA.rC[1] = { yrm2, yrs2, gb2[in], lbj2, fin ? gb2f : gb2[o], WY2[o], 2048 };
        k_comb2<<<176, 256, 0, stream>>>(CA);
    }

    k_final<<<1, 1024, 0, stream>>>(h, hi, hj, f1f, f2f, g1f, gb1f, g2f, gb2f, N, M, out);
}

// Round 7
// 445.831 us; speedup vs baseline: 1.6986x; 1.1421x over previous
//
#include <hip/hip_runtime.h>
#include <math.h>

// ---------------------------------------------------------------------------
// LinSinkhornPRModel: sigmoid(dist2 - dist1) of two Sinkhorn divergences.
//   - f_aa self-term cancels in dist2-dist1 -> C_xx never built.
//   - R6: 16x1024 tiles, dual row+col pass, partial-based updates (509us).
//   - R7: C stored fp16 (halves round reads + cost writes; error ~1e-3 vs
//     4.4e-2 budget); row LSE = in-register two-pass (1 exp2/elem, no serial
//     chain); col LSE online; LDS-tree wave merge (1 barrier).
// ---------------------------------------------------------------------------

typedef __attribute__((ext_vector_type(8))) short short8;
typedef __attribute__((ext_vector_type(4))) float f32x4;
typedef __attribute__((ext_vector_type(8))) unsigned short u16x8;
typedef __attribute__((ext_vector_type(4))) unsigned short u16x4;

#define LOG2E 1.4426950408889634
#define LN2   0.6931471805599453

__device__ __forceinline__ float exp2fast(float x){
#if __has_builtin(__builtin_amdgcn_exp2f)
    return __builtin_amdgcn_exp2f(x);
#else
    return exp2f(x);
#endif
}
__device__ __forceinline__ void lse2_upd(float& m, float& s, float v){
    float M2 = fmaxf(m, v);
    s = s * exp2fast(m - M2) + exp2fast(v - M2);
    m = M2;
}
__device__ __forceinline__ void lse2_merge(float& m, float& s, float mo, float so){
    float M2 = fmaxf(m, mo);
    s = s * exp2fast(m - M2) + so * exp2fast(mo - M2);
    m = M2;
}
__device__ __forceinline__ unsigned short f2bf(float x){
    unsigned u = __float_as_uint(x);
    unsigned r = u + 0x7fffu + ((u >> 16) & 1u);
    return (unsigned short)(r >> 16);
}
__device__ __forceinline__ float bf2f(unsigned short h){
    return __uint_as_float(((unsigned)h) << 16);
}
__device__ __forceinline__ float h2f(unsigned short u){
    _Float16 h; __builtin_memcpy(&h, &u, 2); return (float)h;
}
__device__ __forceinline__ unsigned short f2h(float f){
    _Float16 h = (_Float16)f; unsigned short u; __builtin_memcpy(&u, &h, 2); return u;
}

// ----------------------------- setup kernels -------------------------------

__global__ void k_transposeW(const float* __restrict__ W, float* __restrict__ WT){
    int b = blockIdx.x, t = threadIdx.x;   // WT[k][o] = W[o][k]
    WT[b * 128 + t] = W[t * 128 + b];
}

__global__ __launch_bounds__(128)
void k_transform_all(const float* __restrict__ d, const float* __restrict__ si,
                     const float* __restrict__ sj, const float* __restrict__ WT,
                     unsigned short* __restrict__ th, unsigned short* __restrict__ tl,
                     float* __restrict__ hn)
{
    __shared__ float xs[8][128];
    __shared__ float red[16];
    const int t = threadIdx.x;
    const int r0 = blockIdx.x * 8;
    const float* src; int sr;
    if (r0 < 4096)      { src = d;  sr = r0; }
    else if (r0 < 6144) { src = si; sr = r0 - 4096; }
    else                { src = sj; sr = r0 - 6144; }
    for (int rr = 0; rr < 8; ++rr)
        xs[rr][t] = src[(size_t)(sr + rr) * 128 + t];
    __syncthreads();
    float acc[8];
#pragma unroll
    for (int rr = 0; rr < 8; ++rr) acc[rr] = 0.f;
    for (int k = 0; k < 128; ++k) {
        float wv = WT[k * 128 + t];
#pragma unroll
        for (int rr = 0; rr < 8; ++rr) acc[rr] = fmaf(xs[rr][k], wv, acc[rr]);
    }
#pragma unroll
    for (int rr = 0; rr < 8; ++rr) {
        float a = acc[rr];
        unsigned short hb = f2bf(a);
        th[(size_t)(r0 + rr) * 128 + t] = hb;
        tl[(size_t)(r0 + rr) * 128 + t] = f2bf(a - bf2f(hb));
        float sq = a * a;
#pragma unroll
        for (int o = 1; o < 64; o <<= 1) sq += __shfl_xor(sq, o);
        if ((t & 63) == 0) red[(t >> 6) * 8 + rr] = sq;
    }
    __syncthreads();
    if (t < 8) hn[r0 + t] = 0.5f * (red[t] + red[8 + t]);
}

__global__ void k_log_all(const float* __restrict__ h, const float* __restrict__ hi,
                          const float* __restrict__ hj, float* __restrict__ lg)
{
    int i = blockIdx.x * 256 + threadIdx.x;   // 8192 total
    float x;
    if (i < 4096)      x = h[i];
    else if (i < 6144) x = hi[i - 4096];
    else               x = hj[i - 6144];
    lg[i] = __log2f(x);
}

// ------------------------------ cost GEMM (MFMA) ---------------------------
// C[i][j] = max(hna[i]+hnb[j]-dot(A_i,B_j), 0) stored fp16; dot = hh+hl+lh.
struct CostPair {
    const unsigned short *Ah, *Al, *Bh, *Bl;
    const float *hna, *hnb;
    unsigned short* C; int ldc; int nty;
};
struct CostQuad { CostPair p[4]; };

__global__ __launch_bounds__(256)
void k_cost_mfma(CostQuad Q)
{
    CostPair P = Q.p[blockIdx.z];
    if ((int)blockIdx.y >= P.nty) return;
    const int i0 = blockIdx.y * 128, j0 = blockIdx.x * 128;
    const int w = threadIdx.x >> 6, lane = threadIdx.x & 63;
    const int ar = i0 + (w >> 1) * 64;
    const int bc = j0 + (w & 1) * 64;
    const int lrow = lane & 15;
    const int kgrp = (lane >> 4) * 8;

    f32x4 acc[4][4];
#pragma unroll
    for (int a = 0; a < 4; ++a)
#pragma unroll
        for (int c = 0; c < 4; ++c) acc[a][c] = (f32x4){0.f, 0.f, 0.f, 0.f};

#pragma unroll
    for (int kc = 0; kc < 128; kc += 32) {
        short8 ah[4], al[4], bh[4], bl[4];
#pragma unroll
        for (int f = 0; f < 4; ++f) {
            size_t aoff = (size_t)(ar + f * 16 + lrow) * 128 + kc + kgrp;
            size_t boff = (size_t)(bc + f * 16 + lrow) * 128 + kc + kgrp;
            ah[f] = *reinterpret_cast<const short8*>(P.Ah + aoff);
            al[f] = *reinterpret_cast<const short8*>(P.Al + aoff);
            bh[f] = *reinterpret_cast<const short8*>(P.Bh + boff);
            bl[f] = *reinterpret_cast<const short8*>(P.Bl + boff);
        }
#pragma unroll
        for (int fi = 0; fi < 4; ++fi)
#pragma unroll
            for (int fj = 0; fj < 4; ++fj) {
                acc[fi][fj] = __builtin_amdgcn_mfma_f32_16x16x32_bf16(bh[fj], ah[fi], acc[fi][fj], 0, 0, 0);
                acc[fi][fj] = __builtin_amdgcn_mfma_f32_16x16x32_bf16(bl[fj], ah[fi], acc[fi][fj], 0, 0, 0);
                acc[fi][fj] = __builtin_amdgcn_mfma_f32_16x16x32_bf16(bh[fj], al[fi], acc[fi][fj], 0, 0, 0);
            }
    }
    const int rloc = lane & 15, cloc = (lane >> 4) * 4;
#pragma unroll
    for (int fi = 0; fi < 4; ++fi) {
        int crow = ar + fi * 16 + rloc;
        float ha = P.hna[crow];
#pragma unroll
        for (int fj = 0; fj < 4; ++fj) {
            int ccol = bc + fj * 16 + cloc;
            f32x4 hb = *reinterpret_cast<const f32x4*>(P.hnb + ccol);
            u16x4 v;
#pragma unroll
            for (int e = 0; e < 4; ++e)
                v[e] = f2h(fmaxf(ha + hb[e] - acc[fi][fj][e], 0.f));
            *reinterpret_cast<u16x4*>(P.C + (size_t)crow * P.ldc + ccol) = v;
        }
    }
}

// ------------------------------ round kernel -------------------------------
// Tile 16 rows x 1024 cols (fp16 C). Row LSE: in-register two-pass per row
// (1 exp2/elem). Col LSE: online accumulators per lane-slot, merged across
// waves via one LDS tree. yy tasks: row-only.

struct R3Task {
    const unsigned short* C;            // [rows][2048] fp16
    const float* WB; const float* WA;
    float* pm; float* ps;               // [256][2048]
    float* frm; float* frs;             // [2][4096]
    int blk0;
};
struct R3YTask {
    const unsigned short* C; const float* Wv;
    float* yrm; float* yrs;             // [2][2048]
    int blk0;
};
struct R3Args { R3Task d[2]; R3YTask y[2]; float ie2; int yblk0; };

__global__ __launch_bounds__(256)
void k_round3(R3Args A)
{
    const int b = blockIdx.x;
    const int w = threadIdx.x >> 6, lane = threadIdx.x & 63;
    const float nie2 = -A.ie2;

    if (b >= A.yblk0) {
        // ---- yy row-only tile ----
        R3YTask T = (b >= A.y[1].blk0) ? A.y[1] : A.y[0];
        const int blk = b - T.blk0;
        const int rowchunk = blk >> 1, h = blk & 1;
        const int row0 = rowchunk * 16 + w * 4;
        const int cb = h * 1024;
        float wv0[8], wv1[8];
#pragma unroll
        for (int e = 0; e < 8; ++e) {
            wv0[e] = T.Wv[cb + 8 * lane + e];
            wv1[e] = T.Wv[cb + 512 + 8 * lane + e];
        }
#pragma unroll
        for (int rr = 0; rr < 4; ++rr) {
            const int row = row0 + rr;
            const unsigned short* Cr = T.C + (size_t)row * 2048 + cb;
            u16x8 c0 = *reinterpret_cast<const u16x8*>(Cr + 8 * lane);
            u16x8 c1 = *reinterpret_cast<const u16x8*>(Cr + 512 + 8 * lane);
            float v0[8], v1[8];
#pragma unroll
            for (int e = 0; e < 8; ++e) {
                v0[e] = fmaf(h2f(c0[e]), nie2, wv0[e]);
                v1[e] = fmaf(h2f(c1[e]), nie2, wv1[e]);
            }
            float M = fmaxf(
                fmaxf(fmaxf(fmaxf(v0[0], v0[1]), fmaxf(v0[2], v0[3])),
                      fmaxf(fmaxf(v0[4], v0[5]), fmaxf(v0[6], v0[7]))),
                fmaxf(fmaxf(fmaxf(v1[0], v1[1]), fmaxf(v1[2], v1[3])),
                      fmaxf(fmaxf(v1[4], v1[5]), fmaxf(v1[6], v1[7]))));
#pragma unroll
            for (int o = 1; o < 64; o <<= 1) M = fmaxf(M, __shfl_xor(M, o));
            float s0 = 0.f, s1 = 0.f;
#pragma unroll
            for (int e = 0; e < 8; ++e) {
                s0 += exp2fast(v0[e] - M);
                s1 += exp2fast(v1[e] - M);
            }
            float s = s0 + s1;
#pragma unroll
            for (int o = 1; o < 64; o <<= 1) s += __shfl_xor(s, o);
            if (lane == 0) { T.yrm[h * 2048 + row] = M; T.yrs[h * 2048 + row] = s; }
        }
        return;
    }

    // ---- dual xy tile ----
    __shared__ float lmm[4][1024];
    __shared__ float lss[4][1024];
    R3Task T = (b >= A.d[1].blk0) ? A.d[1] : A.d[0];
    const int blk = b - T.blk0;
    const int rowchunk = blk >> 1, h = blk & 1;
    const int row0 = rowchunk * 16 + w * 4;
    const int cb = h * 1024;
    float wb0[8], wb1[8];
#pragma unroll
    for (int e = 0; e < 8; ++e) {
        wb0[e] = T.WB[cb + 8 * lane + e];
        wb1[e] = T.WB[cb + 512 + 8 * lane + e];
    }
    float mc[16], sc[16];
#pragma unroll
    for (int e = 0; e < 16; ++e) { mc[e] = -INFINITY; sc[e] = 0.f; }

#pragma unroll
    for (int rr = 0; rr < 4; ++rr) {
        const int row = row0 + rr;
        const float wa = T.WA[row];
        const unsigned short* Cr = T.C + (size_t)row * 2048 + cb;
        u16x8 c0 = *reinterpret_cast<const u16x8*>(Cr + 8 * lane);
        u16x8 c1 = *reinterpret_cast<const u16x8*>(Cr + 512 + 8 * lane);
        float v0[8], v1[8];
#pragma unroll
        for (int e = 0; e < 8; ++e) {
            float cf0 = h2f(c0[e]), cf1 = h2f(c1[e]);
            v0[e] = fmaf(cf0, nie2, wb0[e]);
            v1[e] = fmaf(cf1, nie2, wb1[e]);
            lse2_upd(mc[e],     sc[e],     fmaf(cf0, nie2, wa));
            lse2_upd(mc[8 + e], sc[8 + e], fmaf(cf1, nie2, wa));
        }
        float M = fmaxf(
            fmaxf(fmaxf(fmaxf(v0[0], v0[1]), fmaxf(v0[2], v0[3])),
                  fmaxf(fmaxf(v0[4], v0[5]), fmaxf(v0[6], v0[7]))),
            fmaxf(fmaxf(fmaxf(v1[0], v1[1]), fmaxf(v1[2], v1[3])),
                  fmaxf(fmaxf(v1[4], v1[5]), fmaxf(v1[6], v1[7]))));
#pragma unroll
        for (int o = 1; o < 64; o <<= 1) M = fmaxf(M, __shfl_xor(M, o));
        float s0 = 0.f, s1 = 0.f;
#pragma unroll
        for (int e = 0; e < 8; ++e) {
            s0 += exp2fast(v0[e] - M);
            s1 += exp2fast(v1[e] - M);
        }
        float s = s0 + s1;
#pragma unroll
        for (int o = 1; o < 64; o <<= 1) s += __shfl_xor(s, o);
        if (lane == 0) { T.frm[h * 4096 + row] = M; T.frs[h * 4096 + row] = s; }
    }

    // col accumulators -> LDS, one barrier, parallel 4-way merge
#pragma unroll
    for (int e = 0; e < 8; ++e) {
        lmm[w][8 * lane + e] = mc[e];
        lss[w][8 * lane + e] = sc[e];
        lmm[w][512 + 8 * lane + e] = mc[8 + e];
        lss[w][512 + 8 * lane + e] = sc[8 + e];
    }
    __syncthreads();
    {
        const int t = threadIdx.x;           // handles local cols 4t..4t+3
        float om[4], os[4];
#pragma unroll
        for (int j = 0; j < 4; ++j) {
            int c = 4 * t + j;
            float m = lmm[0][c], s = lss[0][c];
            lse2_merge(m, s, lmm[1][c], lss[1][c]);
            lse2_merge(m, s, lmm[2][c], lss[2][c]);
            lse2_merge(m, s, lmm[3][c], lss[3][c]);
            om[j] = m; os[j] = s;
        }
        size_t o = (size_t)rowchunk * 2048 + cb + 4 * t;
        *reinterpret_cast<f32x4*>(T.pm + o) = *reinterpret_cast<const f32x4*>(om);
        *reinterpret_cast<f32x4*>(T.ps + o) = *reinterpret_cast<const f32x4*>(os);
    }
}

// ------------------------------ combine kernel -----------------------------
struct CombA { const float* pm; const float* ps; const float* gold;
               const float* lb; float* gout; float* gwout; };
struct CombR { const float* rm; const float* rs; const float* fold;
               const float* lsf; float* vout; float* wout; int nrows; };
struct C2Args {
    CombA a[2]; CombR rB[2]; CombR rC[2];
    float epsln2, ie2n, alpha, beta;
};

__global__ __launch_bounds__(256)
void k_comb2(C2Args A)
{
    const int b = blockIdx.x;
    const int tid = threadIdx.x;
    const int lane = tid & 63, w = tid >> 6;
    if (b < 128) {
        CombA T = A.a[b >> 6];
        const int bb = b & 63;
        const int jl = tid & 31, cg = tid >> 5;      // 8 chunk groups
        const int j = bb * 32 + jl;
        float m = -INFINITY, s = 0.f;
        for (int c = cg; c < 256; c += 8)
            lse2_merge(m, s, T.pm[(size_t)c * 2048 + j], T.ps[(size_t)c * 2048 + j]);
        {
            float mo = __shfl_xor(m, 32), so = __shfl_xor(s, 32);
            lse2_merge(m, s, mo, so);
        }
        __shared__ float smm[4][32], sss[4][32];
        if (lane < 32) { smm[w][lane] = m; sss[w][lane] = s; }
        __syncthreads();
        if (tid < 32) {
            m = smm[0][tid]; s = sss[0][tid];
            for (int q = 1; q < 4; ++q) lse2_merge(m, s, smm[q][tid], sss[q][tid]);
            float val = -A.epsln2 * (m + __log2f(s));
            float gnew = A.alpha * T.gold[j] + A.beta * val;
            T.gout[j] = gnew;
            T.gwout[j] = fmaf(gnew, A.ie2n, T.lb[j]);
        }
        return;
    }
    CombR T = (b < 160) ? A.rB[(b - 128) >> 4] : A.rC[(b - 160) >> 3];
    const int row = ((b < 160) ? ((b - 128) & 15) : ((b - 160) & 7)) * 256 + tid;
    float m = T.rm[row], s = T.rs[row];
    lse2_merge(m, s, T.rm[T.nrows + row], T.rs[T.nrows + row]);
    float val = -A.epsln2 * (m + __log2f(s));
    float vnew = A.alpha * T.fold[row] + A.beta * val;
    T.vout[row] = vnew;
    T.wout[row] = fmaf(vnew, A.ie2n, T.lsf[row]);
}

// ------------------------------ final reduce -------------------------------
__global__ __launch_bounds__(1024)
void k_final(const float* __restrict__ h, const float* __restrict__ hi,
             const float* __restrict__ hj,
             const float* __restrict__ f1f, const float* __restrict__ f2f,
             const float* __restrict__ g1f, const float* __restrict__ gb1f,
             const float* __restrict__ g2f, const float* __restrict__ gb2f,
             int N, int M, float* __restrict__ out)
{
    float acc = 0.f;
    for (int i = threadIdx.x; i < N; i += 1024)
        acc += h[i] * (f2f[i] - f1f[i]);
    for (int j = threadIdx.x; j < M; j += 1024)
        acc += hj[j] * (g2f[j] - gb2f[j]) - hi[j] * (g1f[j] - gb1f[j]);
#pragma unroll
    for (int o = 32; o; o >>= 1) acc += __shfl_xor(acc, o);
    __shared__ float red[16];
    const int lane = threadIdx.x & 63, w = threadIdx.x >> 6;
    if (lane == 0) red[w] = acc;
    __syncthreads();
    if (threadIdx.x == 0) {
        float t = 0.f;
        for (int q = 0; q < 16; ++q) t += red[q];
        out[0] = 1.f / (1.f + expf(-t));   // SCALING_FACTOR = 1
    }
}

// ------------------------------ orchestration ------------------------------

extern "C" void kernel_launch(void* const* d_in, const int* in_sizes, int n_in,
                              void* d_out, int out_size, void* d_ws, size_t ws_size,
                              hipStream_t stream)
{
    const float* d  = (const float*)d_in[0];
    const float* si = (const float*)d_in[1];
    const float* sj = (const float*)d_in[2];
    const float* h  = (const float*)d_in[3];
    const float* hi = (const float*)d_in[4];
    const float* hj = (const float*)d_in[5];
    const float* W  = (const float*)d_in[6];
    float* out = (float*)d_out;

    const int N = 4096, M = 2048;
    (void)in_sizes; (void)n_in; (void)out_size; (void)ws_size;

    float* ws = (float*)d_ws;
    size_t off = 0;
    auto alloc = [&](size_t n) { float* p = ws + off; off += (n + 63) & ~(size_t)63; return p; };

    float* WT    = alloc(128 * 128);
    float* lg2   = alloc(8192);
    float* hnAll = alloc(8192);
    unsigned short* thAll = (unsigned short*)alloc(8192 * 128 / 2);
    unsigned short* tlAll = (unsigned short*)alloc(8192 * 128 / 2);
    float* f1[2]  = { alloc(N), alloc(N) };
    float* f2[2]  = { alloc(N), alloc(N) };
    float* g1[2]  = { alloc(M), alloc(M) };
    float* g2[2]  = { alloc(M), alloc(M) };
    float* gb1[2] = { alloc(M), alloc(M) };
    float* gb2[2] = { alloc(M), alloc(M) };
    float* WA1[2] = { alloc(N), alloc(N) };
    float* WA2[2] = { alloc(N), alloc(N) };
    float* WB1[2] = { alloc(M), alloc(M) };
    float* WB2[2] = { alloc(M), alloc(M) };
    float* WY1[2] = { alloc(M), alloc(M) };
    float* WY2[2] = { alloc(M), alloc(M) };
    float* f1f = alloc(N); float* f2f = alloc(N);
    float* g1f = alloc(M); float* g2f = alloc(M);
    float* gb1f = alloc(M); float* gb2f = alloc(M);
    unsigned short* C1  = (unsigned short*)alloc((size_t)N * M / 2);
    unsigned short* C2  = (unsigned short*)alloc((size_t)N * M / 2);
    unsigned short* Cy1 = (unsigned short*)alloc((size_t)M * M / 2);
    unsigned short* Cy2 = (unsigned short*)alloc((size_t)M * M / 2);
    float* pm1 = alloc((size_t)256 * 2048);
    float* ps1 = alloc((size_t)256 * 2048);
    float* pm2 = alloc((size_t)256 * 2048);
    float* ps2 = alloc((size_t)256 * 2048);
    float* frm1 = alloc(2 * 4096); float* frs1 = alloc(2 * 4096);
    float* frm2 = alloc(2 * 4096); float* frs2 = alloc(2 * 4096);
    float* yrm1 = alloc(2 * 2048); float* yrs1 = alloc(2 * 2048);
    float* yrm2 = alloc(2 * 2048); float* yrs2 = alloc(2 * 2048);

    float* la2  = lg2;
    float* lbi2 = lg2 + 4096;
    float* lbj2 = lg2 + 6144;
    const float* hnx = hnAll;
    const float* hni = hnAll + 4096;
    const float* hnj = hnAll + 6144;
    const unsigned short* tdh  = thAll;
    const unsigned short* tdl  = tlAll;
    const unsigned short* tsih = thAll + (size_t)4096 * 128;
    const unsigned short* tsil = tlAll + (size_t)4096 * 128;
    const unsigned short* tsjh = thAll + (size_t)6144 * 128;
    const unsigned short* tsjl = tlAll + (size_t)6144 * 128;

    // ---- setup ----
    k_transposeW<<<128, 128, 0, stream>>>(W, WT);
    k_transform_all<<<1024, 128, 0, stream>>>(d, si, sj, WT, thAll, tlAll, hnAll);
    k_log_all<<<32, 256, 0, stream>>>(h, hi, hj, lg2);

    // ---- cost matrices: 4 GEMMs in one launch ----
    CostQuad Q;
    Q.p[0] = { tdh,  tdl,  tsih, tsil, hnx, hni, C1,  M, 32 };
    Q.p[1] = { tdh,  tdl,  tsjh, tsjl, hnx, hnj, C2,  M, 32 };
    Q.p[2] = { tsih, tsil, tsih, tsil, hni, hni, Cy1, M, 16 };
    Q.p[3] = { tsjh, tsjl, tsjh, tsjl, hnj, hnj, Cy2, M, 16 };
    k_cost_mfma<<<dim3(M / 128, N / 128, 4), 256, 0, stream>>>(Q);

    // ---- eps schedule ----
    double epsl[16]; int ne = 0;
    for (double sg = 32.0; sg > 0.05; sg *= 0.5) epsl[ne++] = sg * sg;
    epsl[ne++] = 0.05 * 0.05;   // ne == 11

    for (int r = 0; r <= ne + 1; ++r) {
        const bool init = (r == 0), fin = (r == ne + 1);
        const double eps  = init ? epsl[0] : (fin ? epsl[ne - 1] : epsl[r - 1]);
        const double epsn = (r + 1 <= ne) ? epsl[r] : epsl[ne - 1];
        const int in = init ? 0 : (r - 1) & 1;
        const int o  = r & 1;

        R3Args RA;
        RA.ie2 = (float)(LOG2E / eps);
        RA.yblk0 = 1024;
        RA.d[0] = { C1, init ? lbi2 : WB1[in], init ? la2 : WA1[in], pm1, ps1, frm1, frs1, 0 };
        RA.d[1] = { C2, init ? lbj2 : WB2[in], init ? la2 : WA2[in], pm2, ps2, frm2, frs2, 512 };
        RA.y[0] = { Cy1, init ? lbi2 : WY1[in], yrm1, yrs1, 1024 };
        RA.y[1] = { Cy2, init ? lbj2 : WY2[in], yrm2, yrs2, 1280 };
        k_round3<<<1536, 256, 0, stream>>>(RA);

        C2Args CA;
        CA.epsln2 = (float)(eps * LN2);
        CA.ie2n   = (float)(LOG2E / epsn);
        CA.alpha  = (init || fin) ? 0.0f : 0.5f;
        CA.beta   = (init || fin) ? 1.0f : 0.5f;
        CA.a[0]  = { pm1, ps1, g1[in], lbi2, fin ? g1f : g1[o], WB1[o] };
        CA.a[1]  = { pm2, ps2, g2[in], lbj2, fin ? g2f : g2[o], WB2[o] };
        CA.rB[0] = { frm1, frs1, f1[in], la2, fin ? f1f : f1[o], WA1[o], 4096 };
        CA.rB[1] = { frm2, frs2, f2[in], la2, fin ? f2f : f2[o], WA2[o], 4096 };
        CA.rC[0] = { yrm1, yrs1, gb1[in], lbi2, fin ? gb1f : gb1[o], WY1[o], 2048 };
        CA.rC[1] = { yrm2, yrs2, gb2[in], lbj2, fin ? gb2f : gb2[o], WY2[o], 2048 };
        k_comb2<<<176, 256, 0, stream>>>(CA);
    }

    k_final<<<1, 1024, 0, stream>>>(h, hi, hj, f1f, f2f, g1f, gb1f, g2f, gb2f, N, M, out);
}